// Round 3
// baseline (637.651 us; speedup 1.0000x reference)
//
#include <hip/hip_runtime.h>

// WaveNet_33036888440853: out[b] = sum_c det( mo[b][cfg[c],cfg[c]] ) * W_ci[c]
// mo = x @ W_mo^T.  B=1024, NE=NAO=NMO=128, NC=32, D=64.  All fp32.
// One block (256 thr = 4 waves) per batch b; mo[b] in LDS; 8 dets per wave.
// v4: blocked LU (NB=8). Panel steps do narrow (<=7 col) readlane updates;
// trailing matrix gets a rank-8 update at block end, with the 8 pivot rows
// broadcast through per-wave LDS (same-address ds_read_b128 = free broadcast
// on the LDS pipe) instead of 1792 VALU readlanes. Cooperative in-reg TRSM
// (28 fma) fixes the stale pivot-row trailing parts. Op order per element is
// identical to the rank-1 sequence -> bit-identical results.
// R1/R2 falsified the occupancy theory (VALUBusy 88% = issue-bound); this
// attacks VALU op count: ~11K -> ~6-7K cyc/det.

constexpr int NE  = 128;
constexpr int NAO = 128;
constexpr int D   = 64;

constexpr int MOS = 129;  // mo_ls stride: (129R+c)%32=(R+c)%32 -> ~2-way on gather
constexpr int GS  = 132;  // staging stride: mult of 4 (aligned b128)
constexpr int NB  = 8;    // LU block size
constexpr int UPS = 68;   // panel row stride (mult of 4, rows hit distinct banks)

constexpr float TAU = 0.02f;  // mo entries ~ N(0, 0.2^2); P(|diag|<tau) ~ 8%

__device__ __forceinline__ float readlane_f(float v, int lane) {
  return __int_as_float(__builtin_amdgcn_readlane(__float_as_int(v), lane));
}

__global__ __launch_bounds__(256) void wavenet_kernel(
    const float* __restrict__ x, const float* __restrict__ W_mo,
    const float* __restrict__ W_ci, const int* __restrict__ configs,
    float* __restrict__ out) {
  // mo: 128*129 = 16512 floats. Panel buffers: 4 waves * 8*68 = 2176 floats.
  // Phase-1 staging (2*8*132 = 2112 floats) overlays the panel region.
  __shared__ float smem[16512 + 4 * NB * UPS];
  __shared__ float partial[4];

  float* const mo_ls = smem;
  float* const x_ls  = smem + 16512;         // overlay on panel region
  float* const w_ls  = smem + 16512 + 1056;  // overlay on panel region

  const int t    = threadIdx.x;
  const int b    = blockIdx.x;
  const int lane = t & 63;
  const int w    = t >> 6;

  float* const up = smem + 16512 + w * (NB * UPS);  // this wave's panel buffer

  // ---------------- Phase 1: mo_ls = x[b] @ W_mo^T (128x128) ----------------
  const int tx = t & 15, ty = t >> 4;
  const int c0 = tx * 8, r0 = ty * 8;
  const float* xb = x + (size_t)b * NE * NAO;

  float acc[8][8];
#pragma unroll
  for (int i = 0; i < 8; ++i)
#pragma unroll
    for (int j = 0; j < 8; ++j) acc[i][j] = 0.f;

  const int le = t >> 1;        // staging row 0..127
  const int lh = (t & 1) * 4;   // k-half 0 or 4

  for (int kb = 0; kb < 16; ++kb) {  // BK = 8
    const float4 xv = *reinterpret_cast<const float4*>(xb + le * NAO + kb * 8 + lh);
    const float4 wv = *reinterpret_cast<const float4*>(W_mo + le * NAO + kb * 8 + lh);
    x_ls[(lh + 0) * GS + le] = xv.x;
    x_ls[(lh + 1) * GS + le] = xv.y;
    x_ls[(lh + 2) * GS + le] = xv.z;
    x_ls[(lh + 3) * GS + le] = xv.w;
    w_ls[(lh + 0) * GS + le] = wv.x;
    w_ls[(lh + 1) * GS + le] = wv.y;
    w_ls[(lh + 2) * GS + le] = wv.z;
    w_ls[(lh + 3) * GS + le] = wv.w;
    __syncthreads();
#pragma unroll
    for (int nn = 0; nn < 8; ++nn) {
      const float4 a0 = *reinterpret_cast<const float4*>(&x_ls[nn * GS + r0]);
      const float4 a1 = *reinterpret_cast<const float4*>(&x_ls[nn * GS + r0 + 4]);
      const float4 b0 = *reinterpret_cast<const float4*>(&w_ls[nn * GS + c0]);
      const float4 b1 = *reinterpret_cast<const float4*>(&w_ls[nn * GS + c0 + 4]);
      const float av[8] = {a0.x, a0.y, a0.z, a0.w, a1.x, a1.y, a1.z, a1.w};
      const float bv[8] = {b0.x, b0.y, b0.z, b0.w, b1.x, b1.y, b1.z, b1.w};
#pragma unroll
      for (int i = 0; i < 8; ++i)
#pragma unroll
        for (int j = 0; j < 8; ++j) acc[i][j] = fmaf(av[i], bv[j], acc[i][j]);
    }
    __syncthreads();
  }
#pragma unroll
  for (int i = 0; i < 8; ++i)
#pragma unroll
    for (int j = 0; j < 8; ++j) mo_ls[(r0 + i) * MOS + c0 + j] = acc[i][j];
  __syncthreads();   // mo ready; staging dead -> panel buffers usable

  // ---------------- Phase 2: 8 blocked LUs per wave ------------------------
  float waveacc = 0.f;

#pragma unroll 1
  for (int cc = 0; cc < 8; ++cc) {
    const int c = w * 8 + cc;
    const int cjv     = configs[c * D + lane];  // lane's row config index
    const int rowbase = cjv * MOS;

    float a[64];
#pragma unroll
    for (int j = 0; j < 64; ++j) {
      const int cj = __builtin_amdgcn_readlane(cjv, j);  // column config index
      a[j] = mo_ls[rowbase + cj];
    }

    int myslot = lane;   // virtual row-slot (tracks permutation for sign)
    float det  = 1.f;

#pragma unroll
    for (int tB = 0; tB < 8; ++tB) {
      const int kb  = tB * NB;
      const int wtr = 64 - (kb + NB);  // trailing width after this block

      float mloc[NB];
      int   pl[NB];

      // ---- panel: NB steps, updates restricted to panel columns ----
#pragma unroll
      for (int i = 0; i < NB; ++i) {
        const int k = kb + i;
        const float ak = a[k];
        // pivot selection: diagonal-first threshold pivoting
        unsigned long long dbal = __ballot(myslot == k);
        int   p  = (int)__builtin_ctzll(dbal);
        float pv = readlane_f(ak, p);

        if (!(fabsf(pv) > TAU)) {  // wave-uniform, rare (~8%)
          const bool act = (myslot >= k);
          unsigned long long cbal = __ballot(act && (fabsf(ak) > TAU));
          if (cbal == 0ull) {      // very rare: all candidates tiny -> true max
            float v = act ? fabsf(ak) : -1.f;
#pragma unroll
            for (int off = 32; off; off >>= 1) v = fmaxf(v, __shfl_xor(v, off));
            cbal = __ballot(act && (fabsf(ak) == v));
            if (cbal == 0ull) cbal = __ballot(act);  // paranoia
          }
          p  = (int)__builtin_ctzll(cbal);
          pv = readlane_f(ak, p);
          const int sp = __builtin_amdgcn_readlane(myslot, p);
          if (sp != k) det = -det;
          myslot = (lane == p) ? k : ((myslot == k) ? sp : myslot);
        }

        float invp;
        if (pv != 0.f) {
          invp = __builtin_amdgcn_rcpf(pv);
          invp = invp * (2.f - pv * invp);  // one NR step
          det *= pv;
        } else {
          det  = 0.f;   // singular: freeze (invp=0 -> no-op updates)
          invp = 0.f;
        }

        const float m = (myslot > k) ? ak * invp : 0.f;
        mloc[i] = m;
        pl[i]   = p;
        // narrow update: panel columns only
#pragma unroll
        for (int j = k + 1; j < kb + NB; ++j)
          a[j] = fmaf(-m, readlane_f(a[j], p), a[j]);
      }

      if (wtr > 0) {
        // ---- store raw trailing parts of the 8 pivot rows (8 lanes act) ----
        if (myslot >= kb && myslot < kb + NB) {
          float* dst = up + (myslot - kb) * UPS;
#pragma unroll
          for (int j4 = kb + NB; j4 < 64; j4 += 4) {
            float4 v;
            v.x = a[j4 + 0]; v.y = a[j4 + 1]; v.z = a[j4 + 2]; v.w = a[j4 + 3];
            *reinterpret_cast<float4*>(dst + (j4 - kb - NB)) = v;
          }
        }

        // ---- cooperative TRSM: fix pivot rows 1..7 (forward substitution) --
        if (lane < wtr) {
          float u[NB];
          float* col = up + lane;
#pragma unroll
          for (int tt = 0; tt < NB; ++tt) u[tt] = col[tt * UPS];
#pragma unroll
          for (int i = 1; i < NB; ++i) {
#pragma unroll
            for (int tt = 0; tt < i; ++tt)
              u[i] = fmaf(-readlane_f(mloc[tt], pl[i]), u[tt], u[i]);
          }
#pragma unroll
          for (int i = 1; i < NB; ++i) col[i * UPS] = u[i];
        }

        // ---- rank-8 trailing update, pivot rows via LDS broadcast ----------
#pragma unroll
        for (int j4 = kb + NB; j4 < 64; j4 += 4) {
          const int o = j4 - (kb + NB);
          const float4 q0 = *reinterpret_cast<const float4*>(up + 0 * UPS + o);
          const float4 q1 = *reinterpret_cast<const float4*>(up + 1 * UPS + o);
          const float4 q2 = *reinterpret_cast<const float4*>(up + 2 * UPS + o);
          const float4 q3 = *reinterpret_cast<const float4*>(up + 3 * UPS + o);
          const float4 q4 = *reinterpret_cast<const float4*>(up + 4 * UPS + o);
          const float4 q5 = *reinterpret_cast<const float4*>(up + 5 * UPS + o);
          const float4 q6 = *reinterpret_cast<const float4*>(up + 6 * UPS + o);
          const float4 q7 = *reinterpret_cast<const float4*>(up + 7 * UPS + o);
          a[j4 + 0] = fmaf(-mloc[0], q0.x, a[j4 + 0]);
          a[j4 + 0] = fmaf(-mloc[1], q1.x, a[j4 + 0]);
          a[j4 + 0] = fmaf(-mloc[2], q2.x, a[j4 + 0]);
          a[j4 + 0] = fmaf(-mloc[3], q3.x, a[j4 + 0]);
          a[j4 + 0] = fmaf(-mloc[4], q4.x, a[j4 + 0]);
          a[j4 + 0] = fmaf(-mloc[5], q5.x, a[j4 + 0]);
          a[j4 + 0] = fmaf(-mloc[6], q6.x, a[j4 + 0]);
          a[j4 + 0] = fmaf(-mloc[7], q7.x, a[j4 + 0]);
          a[j4 + 1] = fmaf(-mloc[0], q0.y, a[j4 + 1]);
          a[j4 + 1] = fmaf(-mloc[1], q1.y, a[j4 + 1]);
          a[j4 + 1] = fmaf(-mloc[2], q2.y, a[j4 + 1]);
          a[j4 + 1] = fmaf(-mloc[3], q3.y, a[j4 + 1]);
          a[j4 + 1] = fmaf(-mloc[4], q4.y, a[j4 + 1]);
          a[j4 + 1] = fmaf(-mloc[5], q5.y, a[j4 + 1]);
          a[j4 + 1] = fmaf(-mloc[6], q6.y, a[j4 + 1]);
          a[j4 + 1] = fmaf(-mloc[7], q7.y, a[j4 + 1]);
          a[j4 + 2] = fmaf(-mloc[0], q0.z, a[j4 + 2]);
          a[j4 + 2] = fmaf(-mloc[1], q1.z, a[j4 + 2]);
          a[j4 + 2] = fmaf(-mloc[2], q2.z, a[j4 + 2]);
          a[j4 + 2] = fmaf(-mloc[3], q3.z, a[j4 + 2]);
          a[j4 + 2] = fmaf(-mloc[4], q4.z, a[j4 + 2]);
          a[j4 + 2] = fmaf(-mloc[5], q5.z, a[j4 + 2]);
          a[j4 + 2] = fmaf(-mloc[6], q6.z, a[j4 + 2]);
          a[j4 + 2] = fmaf(-mloc[7], q7.z, a[j4 + 2]);
          a[j4 + 3] = fmaf(-mloc[0], q0.w, a[j4 + 3]);
          a[j4 + 3] = fmaf(-mloc[1], q1.w, a[j4 + 3]);
          a[j4 + 3] = fmaf(-mloc[2], q2.w, a[j4 + 3]);
          a[j4 + 3] = fmaf(-mloc[3], q3.w, a[j4 + 3]);
          a[j4 + 3] = fmaf(-mloc[4], q4.w, a[j4 + 3]);
          a[j4 + 3] = fmaf(-mloc[5], q5.w, a[j4 + 3]);
          a[j4 + 3] = fmaf(-mloc[6], q6.w, a[j4 + 3]);
          a[j4 + 3] = fmaf(-mloc[7], q7.w, a[j4 + 3]);
        }
      }
    }
    waveacc += det * W_ci[c];
  }

  if (lane == 0) partial[w] = waveacc;
  __syncthreads();
  if (t == 0) out[b] = partial[0] + partial[1] + partial[2] + partial[3];
}

extern "C" void kernel_launch(void* const* d_in, const int* in_sizes, int n_in,
                              void* d_out, int out_size, void* d_ws, size_t ws_size,
                              hipStream_t stream) {
  (void)in_sizes; (void)n_in; (void)d_ws; (void)ws_size; (void)out_size;
  const float* x       = (const float*)d_in[0];
  const float* W_mo    = (const float*)d_in[1];
  const float* W_ci    = (const float*)d_in[2];
  const int*   configs = (const int*)d_in[3];
  float*       out     = (float*)d_out;
  hipLaunchKernelGGL(wavenet_kernel, dim3(1024), dim3(256), 0, stream,
                     x, W_mo, W_ci, configs, out);
}